// Round 1
// baseline (1353.258 us; speedup 1.0000x reference)
//
#include <hip/hip_runtime.h>

#define NGRAPHS 512

// ---------------- CSR build ----------------

__global__ void k_hist(const int* __restrict__ dst, int* __restrict__ counts, int nE) {
    int e = blockIdx.x * blockDim.x + threadIdx.x;
    if (e < nE) atomicAdd(&counts[dst[e]], 1);
}

__global__ void k_scan_block(const int* __restrict__ counts, int* __restrict__ incl,
                             int* __restrict__ blockSums, int n) {
    __shared__ int s[256];
    int t = threadIdx.x;
    int idx = blockIdx.x * 256 + t;
    int v = (idx < n) ? counts[idx] : 0;
    s[t] = v;
    __syncthreads();
    for (int off = 1; off < 256; off <<= 1) {
        int x = (t >= off) ? s[t - off] : 0;
        __syncthreads();
        s[t] += x;
        __syncthreads();
    }
    if (idx < n) incl[idx] = s[t];
    if (t == 255) blockSums[blockIdx.x] = s[255];
}

__global__ void k_scan_sums(const int* __restrict__ blockSums, int* __restrict__ blockOffs, int nb) {
    __shared__ int s[512];
    int t = threadIdx.x;
    int v = (t < nb) ? blockSums[t] : 0;
    s[t] = v;
    __syncthreads();
    for (int off = 1; off < 512; off <<= 1) {
        int x = (t >= off) ? s[t - off] : 0;
        __syncthreads();
        s[t] += x;
        __syncthreads();
    }
    if (t < nb) blockOffs[t] = s[t] - v;  // exclusive
}

__global__ void k_finish_csr(const int* __restrict__ counts, const int* __restrict__ incl,
                             const int* __restrict__ blockOffs, int* __restrict__ row_start,
                             int* __restrict__ cursor, float* __restrict__ rdeg, int n, int nE) {
    int i = blockIdx.x * blockDim.x + threadIdx.x;
    if (i < n) {
        int ex = incl[i] - counts[i] + blockOffs[i >> 8];
        row_start[i] = ex;
        cursor[i] = ex;
        int d = counts[i] > 1 ? counts[i] : 1;
        rdeg[i] = 1.0f / (float)d;
    }
    if (i == 0) row_start[n] = nE;
}

__global__ void k_scatter(const int* __restrict__ src, const int* __restrict__ dst,
                          int* __restrict__ cursor, int* __restrict__ col, int nE) {
    int e = blockIdx.x * blockDim.x + threadIdx.x;
    if (e < nE) {
        int p = atomicAdd(&cursor[dst[e]], 1);
        col[p] = src[e];
    }
}

// ---------------- mean aggregation (gather over CSR) ----------------
// one wave (64 lanes) per node; float2 per lane covers the 128-ch row.

__global__ __launch_bounds__(256) void k_agg(const float* __restrict__ h,
                                             const int* __restrict__ row_start,
                                             const int* __restrict__ col,
                                             const float* __restrict__ rdeg,
                                             float* __restrict__ out, int n) {
    int w = (blockIdx.x * blockDim.x + threadIdx.x) >> 6;
    int lane = threadIdx.x & 63;
    if (w >= n) return;
    int s = row_start[w], e = row_start[w + 1];
    float a0 = 0.f, a1 = 0.f;
    int j = s;
    for (; j + 1 < e; j += 2) {
        int s0 = col[j], s1 = col[j + 1];
        float2 v0 = *(const float2*)(h + (size_t)s0 * 128 + lane * 2);
        float2 v1 = *(const float2*)(h + (size_t)s1 * 128 + lane * 2);
        a0 += v0.x + v1.x;
        a1 += v0.y + v1.y;
    }
    if (j < e) {
        int s0 = col[j];
        float2 v0 = *(const float2*)(h + (size_t)s0 * 128 + lane * 2);
        a0 += v0.x;
        a1 += v0.y;
    }
    float r = rdeg[w];
    *(float2*)(out + (size_t)w * 128 + lane * 2) = make_float2(a0 * r, a1 * r);
}

// ---------------- dense transform: out = mean@WnT + h@WsT + b ----------------
// 512 threads; each thread computes 4 output channels of one node.
// W chunks (KC=32 k's) staged transposed in LDS, conflict-free [k][c] layout.

template <int OUTC, bool RELU>
__global__ __launch_bounds__(512) void k_transform(const float* meanbuf, const float* hbuf,
                                                   const float* __restrict__ wn,
                                                   const float* __restrict__ ws,
                                                   const float* __restrict__ bias,
                                                   float* out, int n) {
    constexpr int TPN = OUTC / 4;   // threads per node
    constexpr int NPB = 512 / TPN;  // nodes per block
    constexpr int KC = 32;
    __shared__ float wnT[KC][OUTC];
    __shared__ float wsT[KC][OUTC];
    __shared__ float mrow[NPB][128];
    __shared__ float hrow[NPB][128];

    const int t = threadIdx.x;
    const int slot = t / TPN;
    const int c0 = (t % TPN) * 4;
    const int base = blockIdx.x * NPB;

    // stage node rows (mean + h) into LDS, float4
    for (int i = t; i < NPB * 32; i += 512) {
        int sl = i >> 5;
        int k4 = (i & 31) * 4;
        int nn = base + sl;
        float4 mv, hv;
        if (nn < n) {
            mv = *(const float4*)(meanbuf + (size_t)nn * 128 + k4);
            hv = *(const float4*)(hbuf + (size_t)nn * 128 + k4);
        } else {
            mv = make_float4(0.f, 0.f, 0.f, 0.f);
            hv = mv;
        }
        *(float4*)&mrow[sl][k4] = mv;
        *(float4*)&hrow[sl][k4] = hv;
    }

    float4 bv = *(const float4*)(bias + c0);
    float acc0 = bv.x, acc1 = bv.y, acc2 = bv.z, acc3 = bv.w;

    for (int kc = 0; kc < 128; kc += KC) {
        __syncthreads();  // rows ready (kc=0) / prev chunk consumed (kc>0)
        // stage W^T chunk: lanes write consecutive c -> conflict-free
        for (int i = t; i < (KC * OUTC / 4); i += 512) {
            int c = i % OUTC;
            int k4 = (i / OUTC) * 4;
            float4 a = *(const float4*)(wn + (size_t)c * 128 + kc + k4);
            wnT[k4 + 0][c] = a.x;
            wnT[k4 + 1][c] = a.y;
            wnT[k4 + 2][c] = a.z;
            wnT[k4 + 3][c] = a.w;
            float4 b = *(const float4*)(ws + (size_t)c * 128 + kc + k4);
            wsT[k4 + 0][c] = b.x;
            wsT[k4 + 1][c] = b.y;
            wsT[k4 + 2][c] = b.z;
            wsT[k4 + 3][c] = b.w;
        }
        __syncthreads();
#pragma unroll 8
        for (int k = 0; k < KC; ++k) {
            float m = mrow[slot][kc + k];
            float hh = hrow[slot][kc + k];
            float4 wa = *(const float4*)&wnT[k][c0];
            float4 wb = *(const float4*)&wsT[k][c0];
            acc0 += wa.x * m + wb.x * hh;
            acc1 += wa.y * m + wb.y * hh;
            acc2 += wa.z * m + wb.z * hh;
            acc3 += wa.w * m + wb.w * hh;
        }
    }

    int node = base + slot;
    if (node < n) {
        if (RELU) {
            acc0 = fmaxf(acc0, 0.f);
            acc1 = fmaxf(acc1, 0.f);
            acc2 = fmaxf(acc2, 0.f);
            acc3 = fmaxf(acc3, 0.f);
        }
        *(float4*)(out + (size_t)node * OUTC + c0) = make_float4(acc0, acc1, acc2, acc3);
    }
}

// ---------------- global mean pool ----------------

__global__ __launch_bounds__(256) void k_pool(const float* __restrict__ h,
                                              const int* __restrict__ batch,
                                              float* __restrict__ gsum,
                                              float* __restrict__ gcnt, int n) {
    int w = (blockIdx.x * blockDim.x + threadIdx.x) >> 6;
    int lane = threadIdx.x & 63;
    if (w >= n) return;
    int g = batch[w];
    float v = h[(size_t)w * 64 + lane];
    atomicAdd(&gsum[g * 64 + lane], v);
    if (lane == 0) atomicAdd(&gcnt[g], 1.0f);
}

__global__ void k_final(const float* __restrict__ gsum, const float* __restrict__ gcnt,
                        float* __restrict__ out, int total) {
    int i = blockIdx.x * blockDim.x + threadIdx.x;
    if (i < total) out[i] = gsum[i] / fmaxf(gcnt[i >> 6], 1.0f);
}

// ---------------- launcher ----------------

extern "C" void kernel_launch(void* const* d_in, const int* in_sizes, int n_in,
                              void* d_out, int out_size, void* d_ws, size_t ws_size,
                              hipStream_t stream) {
    const float* x = (const float*)d_in[0];
    const int* ei = (const int*)d_in[1];
    const int* batch = (const int*)d_in[2];
    const float* wn0 = (const float*)d_in[3];
    const float* ws0 = (const float*)d_in[4];
    const float* b0 = (const float*)d_in[5];
    const float* wn1 = (const float*)d_in[6];
    const float* ws1 = (const float*)d_in[7];
    const float* b1 = (const float*)d_in[8];
    const float* wn2 = (const float*)d_in[9];
    const float* ws2 = (const float*)d_in[10];
    const float* b2 = (const float*)d_in[11];

    const int n = in_sizes[0] / 128;  // 100000
    const int nE = in_sizes[1] / 2;   // 1600000
    const int* src = ei;
    const int* dst = ei + nE;

    char* p = (char*)d_ws;
    auto alloc = [&](size_t bytes) {
        void* r = (void*)p;
        p += (bytes + 255) & ~(size_t)255;
        return r;
    };
    int* counts = (int*)alloc((size_t)n * 4);
    int* incl = (int*)alloc((size_t)n * 4);
    int* blockSums = (int*)alloc(4096);
    int* blockOffs = (int*)alloc(4096);
    int* row_start = (int*)alloc((size_t)(n + 1) * 4);
    int* cursor = (int*)alloc((size_t)n * 4);
    float* rdeg = (float*)alloc((size_t)n * 4);
    int* col = (int*)alloc((size_t)nE * 4);
    float* gsum = (float*)alloc((size_t)NGRAPHS * 64 * 4);
    float* gcnt = (float*)alloc((size_t)NGRAPHS * 4);
    float* bufA = (float*)alloc((size_t)n * 128 * 4);
    float* bufB = (float*)alloc((size_t)n * 128 * 4);
    float* bufC = (float*)alloc((size_t)n * 64 * 4);

    hipMemsetAsync(counts, 0, (size_t)n * 4, stream);
    hipMemsetAsync(gsum, 0, (size_t)NGRAPHS * 64 * 4, stream);
    hipMemsetAsync(gcnt, 0, (size_t)NGRAPHS * 4, stream);

    const int tb = 256;
    const int nb = (n + 255) / 256;

    k_hist<<<(nE + tb - 1) / tb, tb, 0, stream>>>(dst, counts, nE);
    k_scan_block<<<nb, 256, 0, stream>>>(counts, incl, blockSums, n);
    k_scan_sums<<<1, 512, 0, stream>>>(blockSums, blockOffs, nb);
    k_finish_csr<<<nb, 256, 0, stream>>>(counts, incl, blockOffs, row_start, cursor, rdeg, n, nE);
    k_scatter<<<(nE + tb - 1) / tb, tb, 0, stream>>>(src, dst, cursor, col, nE);

    const int aggGrid = ((n * 64) + tb - 1) / tb;

    // layer 0: agg(x)->A ; trans(A, x)->B
    k_agg<<<aggGrid, tb, 0, stream>>>(x, row_start, col, rdeg, bufA, n);
    k_transform<128, true><<<(n + 15) / 16, 512, 0, stream>>>(bufA, x, wn0, ws0, b0, bufB, n);
    // layer 1: agg(B)->A ; trans(A, B)->B (row-matched in-place, safe)
    k_agg<<<aggGrid, tb, 0, stream>>>(bufB, row_start, col, rdeg, bufA, n);
    k_transform<128, true><<<(n + 15) / 16, 512, 0, stream>>>(bufA, bufB, wn1, ws1, b1, bufB, n);
    // layer 2: agg(B)->A ; trans(A, B)->C (n x 64)
    k_agg<<<aggGrid, tb, 0, stream>>>(bufB, row_start, col, rdeg, bufA, n);
    k_transform<64, false><<<(n + 31) / 32, 512, 0, stream>>>(bufA, bufB, wn2, ws2, b2, bufC, n);

    // pool
    k_pool<<<aggGrid, tb, 0, stream>>>(bufC, batch, gsum, gcnt, n);
    k_final<<<(NGRAPHS * 64 + 255) / 256, 256, 0, stream>>>(gsum, gcnt, (float*)d_out, NGRAPHS * 64);
}

// Round 2
// 994.784 us; speedup vs baseline: 1.3604x; 1.3604x over previous
//
#include <hip/hip_runtime.h>
#include <hip/hip_bf16.h>

#define NGRAPHS 512

typedef __attribute__((ext_vector_type(8))) short bf16x8;
typedef __attribute__((ext_vector_type(4))) float f32x4;

__device__ inline short f2bf(float x) {
    __hip_bfloat16 h = __float2bfloat16(x);
    return *(short*)&h;
}

// ---------------- CSR build ----------------

__global__ void k_hist(const int* __restrict__ dst, int* __restrict__ counts, int nE) {
    int e = blockIdx.x * blockDim.x + threadIdx.x;
    if (e < nE) atomicAdd(&counts[dst[e]], 1);
}

__global__ void k_scan_block(const int* __restrict__ counts, int* __restrict__ incl,
                             int* __restrict__ blockSums, int n) {
    __shared__ int s[256];
    int t = threadIdx.x;
    int idx = blockIdx.x * 256 + t;
    int v = (idx < n) ? counts[idx] : 0;
    s[t] = v;
    __syncthreads();
    for (int off = 1; off < 256; off <<= 1) {
        int x = (t >= off) ? s[t - off] : 0;
        __syncthreads();
        s[t] += x;
        __syncthreads();
    }
    if (idx < n) incl[idx] = s[t];
    if (t == 255) blockSums[blockIdx.x] = s[255];
}

__global__ void k_scan_sums(const int* __restrict__ blockSums, int* __restrict__ blockOffs, int nb) {
    __shared__ int s[512];
    int t = threadIdx.x;
    int v = (t < nb) ? blockSums[t] : 0;
    s[t] = v;
    __syncthreads();
    for (int off = 1; off < 512; off <<= 1) {
        int x = (t >= off) ? s[t - off] : 0;
        __syncthreads();
        s[t] += x;
        __syncthreads();
    }
    if (t < nb) blockOffs[t] = s[t] - v;  // exclusive
}

__global__ void k_finish_csr(const int* __restrict__ counts, const int* __restrict__ incl,
                             const int* __restrict__ blockOffs, int* __restrict__ row_start,
                             int* __restrict__ cursor, float* __restrict__ rdeg, int n, int nE) {
    int i = blockIdx.x * blockDim.x + threadIdx.x;
    if (i < n) {
        int ex = incl[i] - counts[i] + blockOffs[i >> 8];
        row_start[i] = ex;
        cursor[i] = ex;
        int d = counts[i] > 1 ? counts[i] : 1;
        rdeg[i] = 1.0f / (float)d;
    }
    if (i == 0) row_start[n] = nE;
}

__global__ void k_scatter(const int* __restrict__ src, const int* __restrict__ dst,
                          int* __restrict__ cursor, int* __restrict__ col, int nE) {
    int e = blockIdx.x * blockDim.x + threadIdx.x;
    if (e < nE) {
        int p = atomicAdd(&cursor[dst[e]], 1);
        col[p] = src[e];
    }
}

// ---------------- mean aggregation (gather over CSR) ----------------

__global__ __launch_bounds__(256) void k_agg(const float* __restrict__ h,
                                             const int* __restrict__ row_start,
                                             const int* __restrict__ col,
                                             const float* __restrict__ rdeg,
                                             float* __restrict__ out, int n) {
    int w = (blockIdx.x * blockDim.x + threadIdx.x) >> 6;
    int lane = threadIdx.x & 63;
    if (w >= n) return;
    int s = row_start[w], e = row_start[w + 1];
    float a0 = 0.f, a1 = 0.f;
    int j = s;
    for (; j + 1 < e; j += 2) {
        int s0 = col[j], s1 = col[j + 1];
        float2 v0 = *(const float2*)(h + (size_t)s0 * 128 + lane * 2);
        float2 v1 = *(const float2*)(h + (size_t)s1 * 128 + lane * 2);
        a0 += v0.x + v1.x;
        a1 += v0.y + v1.y;
    }
    if (j < e) {
        int s0 = col[j];
        float2 v0 = *(const float2*)(h + (size_t)s0 * 128 + lane * 2);
        a0 += v0.x;
        a1 += v0.y;
    }
    float r = rdeg[w];
    *(float2*)(out + (size_t)w * 128 + lane * 2) = make_float2(a0 * r, a1 * r);
}

// ---------------- weight prep: split f32 W into bf16 hi+lo, [OUTC][256] ----------------
// whi[c][k] : k<128 -> wn[c][k], k>=128 -> ws[c][k-128]

__global__ void k_wprep(const float* __restrict__ wn, const float* __restrict__ ws,
                        short* __restrict__ whi, short* __restrict__ wlo, int outc) {
    int i = blockIdx.x * 256 + threadIdx.x;
    if (i >= outc * 256) return;
    int c = i >> 8, k = i & 255;
    float w = (k < 128) ? wn[c * 128 + k] : ws[c * 128 + k - 128];
    short hi = f2bf(w);
    __hip_bfloat16 hb = *(__hip_bfloat16*)&hi;
    float hif = __bfloat162float(hb);
    whi[i] = hi;
    wlo[i] = f2bf(w - hif);
}

// ---------------- MFMA transform: out = [mean|h] @ [Wn;Ws]^T + b ----------------
// 4 waves/block. Wave owns NCF*16 output cols (B-stationary in registers, hi+lo).
// Block iterates CHUNK row-tiles of 16 nodes. No LDS, no barriers.
// Fragment k-mapping identical for A and B => any HW-internal k permutation cancels.

template <int OUTC, bool RELU, int CHUNK>
__global__ __launch_bounds__(256, 2) void k_transform_mfma(
    const float* __restrict__ meanbuf, const float* __restrict__ hbuf,
    const bf16x8* __restrict__ whi, const bf16x8* __restrict__ wlo,
    const float* __restrict__ bias, float* __restrict__ out, int n) {
    constexpr int NCF = OUTC / 64;  // colfrags per wave: 128->2, 64->1
    const int wave = threadIdx.x >> 6;
    const int lane = threadIdx.x & 63;
    const int lmod = lane & 15, lgrp = lane >> 4;
    const int n0 = wave * (NCF * 16);

    // B fragments, register-resident: lane holds W[c = n0+cf*16+lmod][k = 32*ks+8*lgrp+e]
    bf16x8 bh[NCF][8], bl[NCF][8];
#pragma unroll
    for (int cf = 0; cf < NCF; ++cf) {
        int c = n0 + cf * 16 + lmod;
#pragma unroll
        for (int ks = 0; ks < 8; ++ks) {
            int idx = c * 32 + ks * 4 + lgrp;  // in bf16x8 units (row = 256 bf16 = 32 units)
            bh[cf][ks] = whi[idx];
            bl[cf][ks] = wlo[idx];
        }
    }

    const int tile0 = blockIdx.x * CHUNK;
    for (int t = 0; t < CHUNK; ++t) {
        int row0 = (tile0 + t) * 16;
        if (row0 >= n) break;
        int m = row0 + lmod;
        const float* mrow = meanbuf + (size_t)m * 128;
        const float* hrow = hbuf + (size_t)m * 128;

        // A fragments: lane holds Acat[m][k = 32*ks+8*lgrp+e], k<128 = mean, else h
        bf16x8 af[8];
#pragma unroll
        for (int ks = 0; ks < 4; ++ks) {
            float4 v0 = *(const float4*)(mrow + ks * 32 + lgrp * 8);
            float4 v1 = *(const float4*)(mrow + ks * 32 + lgrp * 8 + 4);
            bf16x8 a;
            a[0] = f2bf(v0.x); a[1] = f2bf(v0.y); a[2] = f2bf(v0.z); a[3] = f2bf(v0.w);
            a[4] = f2bf(v1.x); a[5] = f2bf(v1.y); a[6] = f2bf(v1.z); a[7] = f2bf(v1.w);
            af[ks] = a;
        }
#pragma unroll
        for (int ks = 0; ks < 4; ++ks) {
            float4 v0 = *(const float4*)(hrow + ks * 32 + lgrp * 8);
            float4 v1 = *(const float4*)(hrow + ks * 32 + lgrp * 8 + 4);
            bf16x8 a;
            a[0] = f2bf(v0.x); a[1] = f2bf(v0.y); a[2] = f2bf(v0.z); a[3] = f2bf(v0.w);
            a[4] = f2bf(v1.x); a[5] = f2bf(v1.y); a[6] = f2bf(v1.z); a[7] = f2bf(v1.w);
            af[4 + ks] = a;
        }

        f32x4 acc[NCF];
#pragma unroll
        for (int cf = 0; cf < NCF; ++cf) acc[cf] = (f32x4){0.f, 0.f, 0.f, 0.f};
#pragma unroll
        for (int ks = 0; ks < 8; ++ks) {
#pragma unroll
            for (int cf = 0; cf < NCF; ++cf) {
                acc[cf] = __builtin_amdgcn_mfma_f32_16x16x32_bf16(af[ks], bh[cf][ks], acc[cf], 0, 0, 0);
                acc[cf] = __builtin_amdgcn_mfma_f32_16x16x32_bf16(af[ks], bl[cf][ks], acc[cf], 0, 0, 0);
            }
        }

        // epilogue: D[row = row0 + lgrp*4 + r][col = n0 + cf*16 + lmod]
#pragma unroll
        for (int cf = 0; cf < NCF; ++cf) {
            int c = n0 + cf * 16 + lmod;
            float bv = bias[c];
#pragma unroll
            for (int r = 0; r < 4; ++r) {
                int rr = row0 + lgrp * 4 + r;
                float v = acc[cf][r] + bv;
                if (RELU) v = fmaxf(v, 0.f);
                out[(size_t)rr * OUTC + c] = v;
            }
        }
    }
}

// ---------------- global mean pool ----------------

__global__ __launch_bounds__(256) void k_pool(const float* __restrict__ h,
                                              const int* __restrict__ batch,
                                              float* __restrict__ gsum,
                                              float* __restrict__ gcnt, int n) {
    int w = (blockIdx.x * blockDim.x + threadIdx.x) >> 6;
    int lane = threadIdx.x & 63;
    if (w >= n) return;
    int g = batch[w];
    float v = h[(size_t)w * 64 + lane];
    atomicAdd(&gsum[g * 64 + lane], v);
    if (lane == 0) atomicAdd(&gcnt[g], 1.0f);
}

__global__ void k_final(const float* __restrict__ gsum, const float* __restrict__ gcnt,
                        float* __restrict__ out, int total) {
    int i = blockIdx.x * blockDim.x + threadIdx.x;
    if (i < total) out[i] = gsum[i] / fmaxf(gcnt[i >> 6], 1.0f);
}

// ---------------- launcher ----------------

extern "C" void kernel_launch(void* const* d_in, const int* in_sizes, int n_in,
                              void* d_out, int out_size, void* d_ws, size_t ws_size,
                              hipStream_t stream) {
    const float* x = (const float*)d_in[0];
    const int* ei = (const int*)d_in[1];
    const int* batch = (const int*)d_in[2];
    const float* wn0 = (const float*)d_in[3];
    const float* ws0 = (const float*)d_in[4];
    const float* b0 = (const float*)d_in[5];
    const float* wn1 = (const float*)d_in[6];
    const float* ws1 = (const float*)d_in[7];
    const float* b1 = (const float*)d_in[8];
    const float* wn2 = (const float*)d_in[9];
    const float* ws2 = (const float*)d_in[10];
    const float* b2 = (const float*)d_in[11];

    const int n = in_sizes[0] / 128;  // 100000
    const int nE = in_sizes[1] / 2;   // 1600000
    const int* src = ei;
    const int* dst = ei + nE;

    char* p = (char*)d_ws;
    auto alloc = [&](size_t bytes) {
        void* r = (void*)p;
        p += (bytes + 255) & ~(size_t)255;
        return r;
    };
    int* counts = (int*)alloc((size_t)n * 4);
    int* incl = (int*)alloc((size_t)n * 4);
    int* blockSums = (int*)alloc(4096);
    int* blockOffs = (int*)alloc(4096);
    int* row_start = (int*)alloc((size_t)(n + 1) * 4);
    int* cursor = (int*)alloc((size_t)n * 4);
    float* rdeg = (float*)alloc((size_t)n * 4);
    int* col = (int*)alloc((size_t)nE * 4);
    float* gsum = (float*)alloc((size_t)NGRAPHS * 64 * 4);
    float* gcnt = (float*)alloc((size_t)NGRAPHS * 4);
    short* whi0 = (short*)alloc(128 * 256 * 2);
    short* wlo0 = (short*)alloc(128 * 256 * 2);
    short* whi1 = (short*)alloc(128 * 256 * 2);
    short* wlo1 = (short*)alloc(128 * 256 * 2);
    short* whi2 = (short*)alloc(64 * 256 * 2);
    short* wlo2 = (short*)alloc(64 * 256 * 2);
    float* bufA = (float*)alloc((size_t)n * 128 * 4);
    float* bufB = (float*)alloc((size_t)n * 128 * 4);
    float* bufC = (float*)alloc((size_t)n * 64 * 4);

    hipMemsetAsync(counts, 0, (size_t)n * 4, stream);
    hipMemsetAsync(gsum, 0, (size_t)NGRAPHS * 64 * 4, stream);
    hipMemsetAsync(gcnt, 0, (size_t)NGRAPHS * 4, stream);

    const int tb = 256;
    const int nb = (n + 255) / 256;

    k_hist<<<(nE + tb - 1) / tb, tb, 0, stream>>>(dst, counts, nE);
    k_scan_block<<<nb, 256, 0, stream>>>(counts, incl, blockSums, n);
    k_scan_sums<<<1, 512, 0, stream>>>(blockSums, blockOffs, nb);
    k_finish_csr<<<nb, 256, 0, stream>>>(counts, incl, blockOffs, row_start, cursor, rdeg, n, nE);
    k_scatter<<<(nE + tb - 1) / tb, tb, 0, stream>>>(src, dst, cursor, col, nE);

    // weight prep (tiny)
    k_wprep<<<(128 * 256 + 255) / 256, 256, 0, stream>>>(wn0, ws0, whi0, wlo0, 128);
    k_wprep<<<(128 * 256 + 255) / 256, 256, 0, stream>>>(wn1, ws1, whi1, wlo1, 128);
    k_wprep<<<(64 * 256 + 255) / 256, 256, 0, stream>>>(wn2, ws2, whi2, wlo2, 64);

    const int aggGrid = ((n * 64) + tb - 1) / tb;
    const int nTiles = (n + 15) / 16;          // 6250
    const int CH = 13;                          // row-tiles per block
    const int tGrid = (nTiles + CH - 1) / CH;   // 481

    // layer 0: agg(x)->A ; trans(A, x)->B
    k_agg<<<aggGrid, tb, 0, stream>>>(x, row_start, col, rdeg, bufA, n);
    k_transform_mfma<128, true, 13><<<tGrid, 256, 0, stream>>>(
        bufA, x, (const bf16x8*)whi0, (const bf16x8*)wlo0, b0, bufB, n);
    // layer 1: agg(B)->A ; trans(A, B)->B (row-matched in-place, safe)
    k_agg<<<aggGrid, tb, 0, stream>>>(bufB, row_start, col, rdeg, bufA, n);
    k_transform_mfma<128, true, 13><<<tGrid, 256, 0, stream>>>(
        bufA, bufB, (const bf16x8*)whi1, (const bf16x8*)wlo1, b1, bufB, n);
    // layer 2: agg(B)->A ; trans(A, B)->C (n x 64)
    k_agg<<<aggGrid, tb, 0, stream>>>(bufB, row_start, col, rdeg, bufA, n);
    k_transform_mfma<64, false, 13><<<tGrid, 256, 0, stream>>>(
        bufA, bufB, (const bf16x8*)whi2, (const bf16x8*)wlo2, b2, bufC, n);

    // pool
    k_pool<<<aggGrid, tb, 0, stream>>>(bufC, batch, gsum, gcnt, n);
    k_final<<<(NGRAPHS * 64 + 255) / 256, 256, 0, stream>>>(gsum, gcnt, (float*)d_out, NGRAPHS * 64);
}